// Round 1
// baseline (596.587 us; speedup 1.0000x reference)
//
#include <hip/hip_runtime.h>

#define B_ 4
#define N_ 16384
#define DIN_ 512
#define H_ 8
#define DH_ 64
#define M_ 32
#define HM_ 256
#define INNER_ 512

typedef _Float16 fp16_t;
typedef _Float16 h8 __attribute__((ext_vector_type(8)));
typedef _Float16 h4 __attribute__((ext_vector_type(4)));
typedef float f4 __attribute__((ext_vector_type(4)));

// ---------------- K0: composite logit weights  Wcomp[hm,k] = (Wslice @ Wx_h)/temp ----
__global__ __launch_bounds__(256) void k0_prep(
    const float* __restrict__ Wx, const float* __restrict__ bx,
    const float* __restrict__ Wslice, const float* __restrict__ bslice,
    const float* __restrict__ temperature,
    fp16_t* __restrict__ Wcomp, float* __restrict__ bcomp) {
  __shared__ float ws[M_ * DH_];
  const int h = blockIdx.x;
  const int tid = threadIdx.x;
  for (int i = tid; i < M_ * DH_; i += 256) ws[i] = Wslice[i];
  __syncthreads();
  const float invt = 1.0f / temperature[h];
  for (int m = 0; m < M_; ++m) {
    for (int k = tid; k < DIN_; k += 256) {
      float acc = 0.f;
      #pragma unroll 16
      for (int d = 0; d < DH_; ++d)
        acc += ws[m * DH_ + d] * Wx[(size_t)(h * DH_ + d) * DIN_ + k];
      Wcomp[(h * M_ + m) * DIN_ + k] = (fp16_t)(acc * invt);
    }
  }
  if (tid < M_) {
    const int m = tid;
    float acc = bslice[m];
    for (int d = 0; d < DH_; ++d) acc += ws[m * DH_ + d] * bx[h * DH_ + d];
    bcomp[h * M_ + m] = acc * invt;
  }
}

// ---------------- K1: logits GEMM + softmax over M, writes w (fp16) + norm atomics --
// block tile: 64 n-rows x 256 hm-cols, 4 waves each own 64 hm cols (2 head groups)
__global__ __launch_bounds__(256) void k1_logits(
    const float* __restrict__ x, const fp16_t* __restrict__ Wcomp,
    const float* __restrict__ bcomp, fp16_t* __restrict__ wout,
    float* __restrict__ norm) {
  __shared__ fp16_t lx[64 * 40];    // [n][32k] stride 40
  __shared__ fp16_t lw[HM_ * 40];   // [hm][32k] stride 40
  const int tid = threadIdx.x;
  const int lane = tid & 63;
  const int wv = tid >> 6;
  const int n0 = blockIdx.x * 64;
  const int b = blockIdx.y;
  f4 acc[4][4] = {};
  const float* xb = x + ((size_t)b * N_ + n0) * DIN_;
  const int lrow = lane & 15;
  const int kb = (lane >> 4) * 8;

  for (int kt = 0; kt < DIN_ / 32; ++kt) {
    const int k0 = kt * 32;
    #pragma unroll
    for (int i = 0; i < 2; ++i) {               // 512 float4 chunks of x
      const int id = tid + i * 256;
      const int row = id >> 3, q = id & 7;
      f4 v = *(const f4*)(xb + (size_t)row * DIN_ + k0 + q * 4);
      h4 hv = {(fp16_t)v.x, (fp16_t)v.y, (fp16_t)v.z, (fp16_t)v.w};
      *(h4*)&lx[row * 40 + q * 4] = hv;
    }
    #pragma unroll
    for (int i = 0; i < 4; ++i) {               // 1024 h8 chunks of Wcomp
      const int id = tid + i * 256;
      const int row = id >> 2, q = id & 3;
      *(h8*)&lw[row * 40 + q * 8] = *(const h8*)(Wcomp + (size_t)row * DIN_ + k0 + q * 8);
    }
    __syncthreads();
    h8 af[4], bf[4];
    #pragma unroll
    for (int t = 0; t < 4; ++t) af[t] = *(const h8*)&lx[(t * 16 + lrow) * 40 + kb];
    #pragma unroll
    for (int t = 0; t < 4; ++t) bf[t] = *(const h8*)&lw[(wv * 64 + t * 16 + lrow) * 40 + kb];
    #pragma unroll
    for (int tn = 0; tn < 4; ++tn)
      #pragma unroll
      for (int tc = 0; tc < 4; ++tc)
        acc[tn][tc] = __builtin_amdgcn_mfma_f32_16x16x32_f16(af[tn], bf[tc], acc[tn][tc], 0, 0, 0);
    __syncthreads();
  }

  // softmax over the 32 m's of each head group; D layout: col=lane&15, row=(lane>>4)*4+r
  const int hm_base = wv * 64;
  const int col = lane & 15;
  const int rgrp = (lane >> 4) * 4;
  #pragma unroll
  for (int s = 0; s < 2; ++s) {
    const float bc0 = bcomp[hm_base + s * 32 + col];
    const float bc1 = bcomp[hm_base + s * 32 + 16 + col];
    float p0 = 0.f, p1 = 0.f;
    #pragma unroll
    for (int tn = 0; tn < 4; ++tn) {
      #pragma unroll
      for (int r = 0; r < 4; ++r) {
        float v0 = acc[tn][2 * s][r] + bc0;
        float v1 = acc[tn][2 * s + 1][r] + bc1;
        float mx = fmaxf(v0, v1);
        mx = fmaxf(mx, __shfl_xor(mx, 1));
        mx = fmaxf(mx, __shfl_xor(mx, 2));
        mx = fmaxf(mx, __shfl_xor(mx, 4));
        mx = fmaxf(mx, __shfl_xor(mx, 8));
        const float e0 = __expf(v0 - mx), e1 = __expf(v1 - mx);
        float sm = e0 + e1;
        sm += __shfl_xor(sm, 1);
        sm += __shfl_xor(sm, 2);
        sm += __shfl_xor(sm, 4);
        sm += __shfl_xor(sm, 8);
        const float inv = __builtin_amdgcn_rcpf(sm);
        const float w0 = e0 * inv, w1 = e1 * inv;
        const int n = n0 + tn * 16 + rgrp + r;
        const size_t base = ((size_t)b * N_ + n) * HM_ + hm_base + s * 32 + col;
        wout[base] = (fp16_t)w0;
        wout[base + 16] = (fp16_t)w1;
        p0 += w0; p1 += w1;
      }
    }
    p0 += __shfl_xor(p0, 16); p0 += __shfl_xor(p0, 32);
    p1 += __shfl_xor(p1, 16); p1 += __shfl_xor(p1, 32);
    if (lane < 16) {
      atomicAdd(&norm[b * HM_ + hm_base + s * 32 + lane], p0);
      atomicAdd(&norm[b * HM_ + hm_base + s * 32 + 16 + lane], p1);
    }
  }
}

// ---------------- K2: S[b,hm,k] = sum_n w[b,n,hm] * x[b,n,k]  (split-K over n) ------
// grid.x: 8 = (hm-tile 2) x (k-tile 4); grid.y: 8 n-chunks of 2048; grid.z: b
__global__ __launch_bounds__(256) void k2_S(
    const float* __restrict__ x, const fp16_t* __restrict__ w,
    float* __restrict__ S) {
  __shared__ fp16_t lw[128 * 40];   // [hm][32n] transposed
  __shared__ fp16_t lx[128 * 40];   // [k][32n] transposed
  const int tid = threadIdx.x, lane = tid & 63, wv = tid >> 6;
  const int hm0 = (blockIdx.x & 1) * 128;
  const int kc0 = (blockIdx.x >> 1) * 128;
  const int nbeg = blockIdx.y * (N_ / 8);
  const int b = blockIdx.z;
  f4 acc[4][4] = {};
  const fp16_t* wb = w + (size_t)b * N_ * HM_;
  const float* xb = x + (size_t)b * N_ * DIN_;
  const int cidx = tid & 127;
  const int ng = (tid >> 7) * 16;
  const int lr = lane & 15;
  const int kb = (lane >> 4) * 8;
  const int hmw = (wv & 1) * 64, kw = (wv >> 1) * 64;

  for (int it = 0; it < 2048 / 32; ++it) {
    const int nn = nbeg + it * 32;
    alignas(16) fp16_t tw[16];
    #pragma unroll
    for (int j = 0; j < 16; ++j)
      tw[j] = wb[(size_t)(nn + ng + j) * HM_ + hm0 + cidx];
    *(h8*)&lw[cidx * 40 + ng] = *(h8*)&tw[0];
    *(h8*)&lw[cidx * 40 + ng + 8] = *(h8*)&tw[8];
    alignas(16) fp16_t tx[16];
    #pragma unroll
    for (int j = 0; j < 16; ++j)
      tx[j] = (fp16_t)xb[(size_t)(nn + ng + j) * DIN_ + kc0 + cidx];
    *(h8*)&lx[cidx * 40 + ng] = *(h8*)&tx[0];
    *(h8*)&lx[cidx * 40 + ng + 8] = *(h8*)&tx[8];
    __syncthreads();
    h8 af[4], bf[4];
    #pragma unroll
    for (int t = 0; t < 4; ++t) af[t] = *(const h8*)&lw[(hmw + t * 16 + lr) * 40 + kb];
    #pragma unroll
    for (int t = 0; t < 4; ++t) bf[t] = *(const h8*)&lx[(kw + t * 16 + lr) * 40 + kb];
    #pragma unroll
    for (int tn = 0; tn < 4; ++tn)
      #pragma unroll
      for (int tc = 0; tc < 4; ++tc)
        acc[tn][tc] = __builtin_amdgcn_mfma_f32_16x16x32_f16(af[tn], bf[tc], acc[tn][tc], 0, 0, 0);
    __syncthreads();
  }
  const int rg = (lane >> 4) * 4;
  #pragma unroll
  for (int tn = 0; tn < 4; ++tn)
    #pragma unroll
    for (int tc = 0; tc < 4; ++tc)
      #pragma unroll
      for (int r = 0; r < 4; ++r) {
        const int hm = hm0 + hmw + tn * 16 + rg + r;
        const int k = kc0 + kw + tc * 16 + lr;
        atomicAdd(&S[((size_t)b * HM_ + hm) * DIN_ + k], acc[tn][tc][r]);
      }
}

// ---------------- K3a: slice_token[b,h,m,d] = (S.Wfx + bfx*norm)/(norm+1e-5) --------
__global__ __launch_bounds__(256) void k3a_st(
    const float* __restrict__ S, const float* __restrict__ Wfx,
    const float* __restrict__ bfx, const float* __restrict__ norm,
    float* __restrict__ st) {
  const int mq = blockIdx.x;          // 8 chunks of 4 m
  const int h = blockIdx.y;
  const int b = blockIdx.z;
  const int tid = threadIdx.x;
  const int m = mq * 4 + (tid >> 6);
  const int d = tid & 63;
  const float* sr = S + ((size_t)b * HM_ + h * M_ + m) * DIN_;
  const float* wr = Wfx + (size_t)(h * DH_ + d) * DIN_;
  float acc = 0.f;
  #pragma unroll 8
  for (int k = 0; k < DIN_; k += 4) {
    f4 a = *(const f4*)(sr + k);
    f4 bb = *(const f4*)(wr + k);
    acc += a.x * bb.x + a.y * bb.y + a.z * bb.z + a.w * bb.w;
  }
  const float nr = norm[b * HM_ + h * M_ + m];
  st[(((size_t)b * H_ + h) * M_ + m) * DH_ + d] =
      (acc + bfx[h * DH_ + d] * nr) / (nr + 1e-5f);
}

// ---------------- K3b: tiny M=32 attention per (b,h) --------------------------------
__global__ __launch_bounds__(256) void k3b_attn(
    const float* __restrict__ st_g, const float* __restrict__ Wq,
    const float* __restrict__ Wk, const float* __restrict__ Wv,
    float* __restrict__ os_g) {
  __shared__ float st[32][65], qs[32][65], ks[32][65], vs[32][65], at[32][33];
  const int h = blockIdx.x, b = blockIdx.y, tid = threadIdx.x;
  const float* stp = st_g + ((size_t)b * H_ + h) * M_ * DH_;
  for (int i = tid; i < 2048; i += 256) st[i >> 6][i & 63] = stp[i];
  __syncthreads();
  for (int i = tid; i < 2048; i += 256) {
    const int m = i >> 6, d = i & 63;
    float aq = 0, ak = 0, av = 0;
    #pragma unroll 8
    for (int dd = 0; dd < 64; ++dd) {
      const float s = st[m][dd];
      aq += s * Wq[d * 64 + dd];
      ak += s * Wk[d * 64 + dd];
      av += s * Wv[d * 64 + dd];
    }
    qs[m][d] = aq; ks[m][d] = ak; vs[m][d] = av;
  }
  __syncthreads();
  for (int i = tid; i < 1024; i += 256) {
    const int m = i >> 5, j = i & 31;
    float a = 0;
    #pragma unroll 8
    for (int d = 0; d < 64; ++d) a += qs[m][d] * ks[j][d];
    at[m][j] = a * 0.125f;
  }
  __syncthreads();
  if (tid < 32) {
    const int m = tid;
    float mx = -1e30f;
    for (int j = 0; j < 32; ++j) mx = fmaxf(mx, at[m][j]);
    float sm = 0;
    for (int j = 0; j < 32; ++j) { const float e = __expf(at[m][j] - mx); at[m][j] = e; sm += e; }
    const float inv = 1.0f / sm;
    for (int j = 0; j < 32; ++j) at[m][j] *= inv;
  }
  __syncthreads();
  float* osp = os_g + ((size_t)b * H_ + h) * M_ * DH_;
  for (int i = tid; i < 2048; i += 256) {
    const int m = i >> 6, d = i & 63;
    float a = 0;
    #pragma unroll 8
    for (int j = 0; j < 32; ++j) a += at[m][j] * vs[j][d];
    osp[i] = a;
  }
}

// ---------------- K3c: Ct[b,kk,hm] = sum_d os[b,h,m,d] * Wout[kk, h*64+d] -----------
__global__ __launch_bounds__(256) void k3c_ct(
    const float* __restrict__ os_g, const float* __restrict__ Wout,
    fp16_t* __restrict__ Ct) {
  const int kc = blockIdx.x;          // 32 chunks of 16 kk
  const int b = blockIdx.y;
  const int tid = threadIdx.x;
  #pragma unroll
  for (int i = 0; i < 16; ++i) {
    const int idx = tid + i * 256;
    const int hm = idx & 255, kkl = idx >> 8;
    const int kk = kc * 16 + kkl;
    const int h = hm >> 5, m = hm & 31;
    const float* op = os_g + (((size_t)b * H_ + h) * M_ + m) * DH_;
    const float* wp = Wout + (size_t)kk * INNER_ + h * DH_;
    float acc = 0.f;
    #pragma unroll
    for (int d = 0; d < 64; d += 4) {
      f4 a = *(const f4*)(op + d);
      f4 w4 = *(const f4*)(wp + d);
      acc += a.x * w4.x + a.y * w4.y + a.z * w4.z + a.w * w4.w;
    }
    Ct[((size_t)b * DIN_ + kk) * HM_ + hm] = (fp16_t)acc;
  }
}

// ---------------- K4: out[b,n,kk] = w[b,n,:] . Ct[b,kk,:] + bout[kk] ----------------
__global__ __launch_bounds__(256) void k4_out(
    const fp16_t* __restrict__ w, const fp16_t* __restrict__ Ct,
    const float* __restrict__ bout, float* __restrict__ out) {
  __shared__ fp16_t la[128 * 40];   // w tile [n][32hm]
  __shared__ fp16_t lb[128 * 40];   // Ct tile [kk][32hm]
  const int tid = threadIdx.x, lane = tid & 63, wv = tid >> 6;
  const int kk0 = blockIdx.x * 128;
  const int n0 = blockIdx.y * 128;
  const int b = blockIdx.z;
  f4 acc[4][4] = {};
  const fp16_t* wb = w + ((size_t)b * N_ + n0) * HM_;
  const fp16_t* cb = Ct + ((size_t)b * DIN_ + kk0) * HM_;
  const int lr = lane & 15;
  const int kb = (lane >> 4) * 8;
  const int nh = (wv & 1) * 64, kh = (wv >> 1) * 64;

  for (int kt = 0; kt < HM_ / 32; ++kt) {
    const int k0 = kt * 32;
    #pragma unroll
    for (int i = 0; i < 2; ++i) {
      const int id = tid + i * 256;
      const int row = id >> 2, q = id & 3;
      *(h8*)&la[row * 40 + q * 8] = *(const h8*)(wb + (size_t)row * HM_ + k0 + q * 8);
    }
    #pragma unroll
    for (int i = 0; i < 2; ++i) {
      const int id = tid + i * 256;
      const int row = id >> 2, q = id & 3;
      *(h8*)&lb[row * 40 + q * 8] = *(const h8*)(cb + (size_t)row * HM_ + k0 + q * 8);
    }
    __syncthreads();
    h8 af[4], bf[4];
    #pragma unroll
    for (int t = 0; t < 4; ++t) af[t] = *(const h8*)&la[(nh + t * 16 + lr) * 40 + kb];
    #pragma unroll
    for (int t = 0; t < 4; ++t) bf[t] = *(const h8*)&lb[(kh + t * 16 + lr) * 40 + kb];
    #pragma unroll
    for (int tn = 0; tn < 4; ++tn)
      #pragma unroll
      for (int tc = 0; tc < 4; ++tc)
        acc[tn][tc] = __builtin_amdgcn_mfma_f32_16x16x32_f16(af[tn], bf[tc], acc[tn][tc], 0, 0, 0);
    __syncthreads();
  }
  const int rg = (lane >> 4) * 4;
  #pragma unroll
  for (int tc = 0; tc < 4; ++tc) {
    const int kk = kk0 + kh + tc * 16 + lr;
    const float bo = bout[kk];
    #pragma unroll
    for (int tn = 0; tn < 4; ++tn)
      #pragma unroll
      for (int r = 0; r < 4; ++r) {
        const int n = n0 + nh + tn * 16 + rg + r;
        out[((size_t)b * N_ + n) * DIN_ + kk] = acc[tn][tc][r] + bo;
      }
  }
}

extern "C" void kernel_launch(void* const* d_in, const int* in_sizes, int n_in,
                              void* d_out, int out_size, void* d_ws, size_t ws_size,
                              hipStream_t stream) {
  (void)in_sizes; (void)n_in; (void)out_size; (void)ws_size;
  const float* x       = (const float*)d_in[0];
  const float* Wx      = (const float*)d_in[1];
  const float* bx      = (const float*)d_in[2];
  const float* Wfx     = (const float*)d_in[3];
  const float* bfx     = (const float*)d_in[4];
  const float* Wslice  = (const float*)d_in[5];
  const float* bslice  = (const float*)d_in[6];
  const float* Wq      = (const float*)d_in[7];
  const float* Wk      = (const float*)d_in[8];
  const float* Wv      = (const float*)d_in[9];
  const float* Wout    = (const float*)d_in[10];
  const float* bout    = (const float*)d_in[11];
  const float* temp    = (const float*)d_in[12];
  float* out = (float*)d_out;

  char* ws = (char*)d_ws;
  fp16_t* wbuf  = (fp16_t*)ws;                    // 33,554,432 B : w [B][N][256] fp16
  float*  S     = (float*)(ws + 33554432);        //  2,097,152 B : S [B][256][512] f32
  float*  norm  = (float*)(ws + 35651584);        //      4,096 B
  float*  st    = (float*)(ws + 35655680);        //    262,144 B
  float*  os    = (float*)(ws + 35917824);        //    262,144 B
  fp16_t* Ct    = (fp16_t*)(ws + 36179968);       //  1,048,576 B : Ct [B][512][256] fp16
  fp16_t* Wcomp = (fp16_t*)(ws + 37228544);       //    262,144 B
  float*  bcomp = (float*)(ws + 37490688);        //      1,024 B

  hipMemsetAsync(S, 0, (size_t)B_ * HM_ * DIN_ * 4, stream);
  hipMemsetAsync(norm, 0, (size_t)B_ * HM_ * 4, stream);
  k0_prep<<<dim3(H_), 256, 0, stream>>>(Wx, bx, Wslice, bslice, temp, Wcomp, bcomp);
  k1_logits<<<dim3(N_ / 64, B_), 256, 0, stream>>>(x, Wcomp, bcomp, wbuf, norm);
  k2_S<<<dim3(8, 8, B_), 256, 0, stream>>>(x, wbuf, S);
  k3a_st<<<dim3(8, H_, B_), 256, 0, stream>>>(S, Wfx, bfx, norm, st);
  k3b_attn<<<dim3(H_, B_), 256, 0, stream>>>(st, Wq, Wk, Wv, os);
  k3c_ct<<<dim3(32, B_), 256, 0, stream>>>(os, Wout, Ct);
  k4_out<<<dim3(DIN_ / 128, N_ / 128, B_), 256, 0, stream>>>(wbuf, Ct, bout, out);
}